// Round 2
// baseline (1904.470 us; speedup 1.0000x reference)
//
#include <hip/hip_runtime.h>
#include <cstdio>
#include <cstdint>

// ---------------- problem constants ----------------
#define T_TOK 16384
#define H_DIM 2048
#define E_NUM 16
#define I_DIM 1408
#define TWO_I 2816
#define BM    256       // GEMM tile M = N = 256, BK = 64
#define BK    64
#define PMAX  36864     // 2*T + E*256: upper bound on padded slot count
#define MAXMT 144       // upper bound on m-tiles: 2*T/256 + E
#define NX1   11        // gemm1 n-blocks: 2816/256
#define NX2   8         // gemm2 n-blocks: 2048/256

typedef unsigned short ushort_t;
typedef __attribute__((ext_vector_type(8))) short bf16x8;
typedef __attribute__((ext_vector_type(4))) float f32x4;
typedef __attribute__((ext_vector_type(8))) unsigned short us8;

__device__ __forceinline__ ushort_t f2bf(float x) {
  union { float f; unsigned int u; } v; v.f = x;
  unsigned int r = v.u + 0x7fffu + ((v.u >> 16) & 1u);   // RNE
  return (ushort_t)(r >> 16);
}

__device__ __forceinline__ float bf2f(ushort_t u) {
  union { unsigned int i; float f; } v; v.i = ((unsigned int)u) << 16; return v.f;
}

__device__ __forceinline__ void async_copy16(const void* g, void* l) {
  __builtin_amdgcn_global_load_lds(
      (const __attribute__((address_space(1))) unsigned int*)g,
      (__attribute__((address_space(3))) unsigned int*)l, 16, 0, 0);
}

// ---------------- routing ----------------
__global__ void zero_small(int* counts, int* fill, int* ntl) {
  int i = threadIdx.x;
  if (i < E_NUM) { counts[i] = 0; fill[i] = 0; }
  if (i == 0) ntl[0] = 0;
}

__global__ void router_kernel(const float* __restrict__ logits,
                              int* __restrict__ tok_e, float* __restrict__ tok_w,
                              int* __restrict__ counts) {
  int t = blockIdx.x * 256 + threadIdx.x;
  if (t >= T_TOK) return;
  const float* lp = logits + (size_t)t * E_NUM;
  float b1 = -1e30f, b2 = -1e30f; int i1 = 0, i2 = 0;
#pragma unroll
  for (int e = 0; e < E_NUM; ++e) {
    float v = lp[e];
    if (v > b1) { b2 = b1; i2 = i1; b1 = v; i1 = e; }
    else if (v > b2) { b2 = v; i2 = e; }
  }
  float w1 = 1.f / (1.f + __expf(b2 - b1));
  tok_e[2 * t] = i1; tok_e[2 * t + 1] = i2;
  tok_w[2 * t] = w1; tok_w[2 * t + 1] = 1.f - w1;
  atomicAdd(&counts[i1], 1);
  atomicAdd(&counts[i2], 1);
}

// wave-parallel: lane e handles expert e; 256-padded tiles
__global__ void scan_kernel(const int* __restrict__ counts, int* __restrict__ base_e,
                            int* __restrict__ tile_expert, int* __restrict__ ntl) {
  int lane = threadIdx.x;
  int c = (lane < E_NUM) ? counts[lane] : 0;
  int tiles = (c + 255) >> 8;
  int pre = 0;
#pragma unroll
  for (int k = 0; k < E_NUM; ++k) {
    int tk = __shfl(tiles, k, 64);
    if (k < lane) pre += tk;
  }
  if (lane < E_NUM) {
    base_e[lane] = pre << 8;
    for (int ti = 0; ti < tiles; ++ti) tile_expert[pre + ti] = lane;
    if (lane == E_NUM - 1) ntl[0] = pre + tiles;
  }
}

__global__ void slot_init_kernel(int* st, float* sw) {
  int i = blockIdx.x * 256 + threadIdx.x;
  if (i < PMAX) { st[i] = 0; sw[i] = 0.f; }   // pad slots: token 0, weight 0
}

__global__ void scatter_kernel(const int* __restrict__ tok_e, const float* __restrict__ tok_w,
                               const int* __restrict__ base_e, int* __restrict__ fill,
                               int* __restrict__ st, float* __restrict__ sw,
                               int* __restrict__ tslot) {
  int t = blockIdx.x * 256 + threadIdx.x;
  if (t >= T_TOK) return;
#pragma unroll
  for (int k = 0; k < 2; ++k) {
    int e = tok_e[2 * t + k];
    int pos = atomicAdd(&fill[e], 1);
    int slot = base_e[e] + pos;
    st[slot] = t; sw[slot] = tok_w[2 * t + k];
    tslot[2 * t + k] = slot;
  }
}

// ---------------- fp32 -> bf16 conversion ----------------
__device__ __forceinline__ us8 pack8(float4 a, float4 b) {
  us8 r;
  r[0] = f2bf(a.x); r[1] = f2bf(a.y); r[2] = f2bf(a.z); r[3] = f2bf(a.w);
  r[4] = f2bf(b.x); r[5] = f2bf(b.y); r[6] = f2bf(b.z); r[7] = f2bf(b.w);
  return r;
}

__global__ void cvt_hidden(const float* __restrict__ src, ushort_t* __restrict__ dst) {
  size_t i8 = ((size_t)blockIdx.x * 256 + threadIdx.x) * 8;
  const float4* s = (const float4*)(src + i8);
  *(us8*)(dst + i8) = pack8(s[0], s[1]);
}

// permute w13 rows: gate row n -> (n/16)*32 + n%16 ; up row n -> ((n-I)/16)*32 + 16 + (n-I)%16
__global__ void cvt_w13(const float* __restrict__ src, ushort_t* __restrict__ dst) {
  size_t i8 = ((size_t)blockIdx.x * 256 + threadIdx.x) * 8;
  const size_t per_e = (size_t)TWO_I * H_DIM;
  int e = (int)(i8 / per_e);
  size_t rem = i8 - (size_t)e * per_e;
  int n = (int)(rem / H_DIM);
  int c = (int)(rem - (size_t)n * H_DIM);
  int np;
  if (n < I_DIM) np = ((n >> 4) << 5) + (n & 15);
  else { int m = n - I_DIM; np = ((m >> 4) << 5) + 16 + (m & 15); }
  const float4* s = (const float4*)(src + i8);
  *(us8*)(dst + (size_t)e * per_e + (size_t)np * H_DIM + c) = pack8(s[0], s[1]);
}

__global__ void cvt_w2(const float* __restrict__ src, ushort_t* __restrict__ dst) {
  size_t i8 = ((size_t)blockIdx.x * 256 + threadIdx.x) * 8;
  const float4* s = (const float4*)(src + i8);
  *(us8*)(dst + i8) = pack8(s[0], s[1]);
}

// ============================================================================
// 256x256 deep-pipelined GEMM (8 waves, BK=64, dbuf LDS, counted vmcnt,
// raw s_barrier, setprio around MFMA clusters). XOR cell-swizzle: 16B cell
// (row m, chunk kc) at unit m*8 + (kc ^ (m&7)) -> conflict-free ds_read_b128
// AND lane-linear global_load_lds staging (pre-swizzled global source).
// ============================================================================

// ---------------- GEMM1: act = silu(X @ W1^T) * (X @ W3^T), token-gathered A --
__global__ __launch_bounds__(512, 2) void gemm1_kernel(
    const ushort_t* __restrict__ Xb, const ushort_t* __restrict__ W13p,
    ushort_t* __restrict__ Act, const int* __restrict__ slot_token,
    const int* __restrict__ tile_expert, const int* __restrict__ ntl) {
  // bijective XCD swizzle over full grid (1584 = 8*198)
  const int bid = blockIdx.x;
  const int wg = (bid & 7) * (NX1 * MAXMT / 8) + (bid >> 3);
  const int mt = wg / NX1;
  const int nb = wg - mt * NX1;
  if (mt >= ntl[0]) return;
  const int e = tile_expert[mt];
  const int slot0 = mt * BM;
  const int n0 = nb * BM;

  __shared__ ushort_t As[2][BM * BK];   // 2 x 32 KiB
  __shared__ ushort_t Bs[2][BM * BK];   // 2 x 32 KiB
  __shared__ int toks[BM];

  const int tid = threadIdx.x;
  if (tid < BM) toks[tid] = slot_token[slot0 + tid];
  __syncthreads();

  const int wave = tid >> 6;
  const int lane = tid & 63;
  const int r = lane & 15;
  const int q = lane >> 4;
  const int wm = wave >> 2;   // 0..1 : M half (128 rows)
  const int wn = wave & 3;    // 0..3 : N quarter (64 cols)

  // staging: 2048 16B units per tile, 4 per thread
  const ushort_t* a_src[4];
  const ushort_t* b_src[4];
  int dst_u[4];
#pragma unroll
  for (int s = 0; s < 4; ++s) {
    int u = s * 512 + tid;
    int m = u >> 3;
    int kc = (u & 7) ^ (m & 7);
    a_src[s] = Xb + (size_t)toks[m] * H_DIM + kc * 8;
    b_src[s] = W13p + (size_t)e * ((size_t)TWO_I * H_DIM) + (size_t)(n0 + m) * H_DIM + kc * 8;
    dst_u[s] = u * 8;
  }

  // ds_read offsets (ushort units); ks=1 offset = ks=0 ^ 32
  int aoff[8], boff[4];
#pragma unroll
  for (int i = 0; i < 8; ++i) {
    int m = wm * 128 + i * 16 + r;
    aoff[i] = (m * 8 + (q ^ (m & 7))) * 8;
  }
#pragma unroll
  for (int j = 0; j < 4; ++j) {
    int n = wn * 64 + j * 16 + r;
    boff[j] = (n * 8 + (q ^ (n & 7))) * 8;
  }

  f32x4 acc[8][4];
#pragma unroll
  for (int i = 0; i < 8; ++i)
#pragma unroll
    for (int j = 0; j < 4; ++j) acc[i][j] = (f32x4)(0.f);

  const int NT = H_DIM / BK;   // 32

  // prologue: stage tile 0 into buf 0
#pragma unroll
  for (int s = 0; s < 4; ++s) {
    async_copy16(a_src[s], &As[0][dst_u[s]]);
    async_copy16(b_src[s], &Bs[0][dst_u[s]]);
  }

  for (int t = 0; t < NT; ++t) {
    const int cur = t & 1;
    const int nxt = cur ^ 1;
    if (t + 1 < NT) {
      const int koff = (t + 1) * BK;
#pragma unroll
      for (int s = 0; s < 4; ++s) {
        async_copy16(a_src[s] + koff, &As[nxt][dst_u[s]]);
        async_copy16(b_src[s] + koff, &Bs[nxt][dst_u[s]]);
      }
      asm volatile("s_waitcnt vmcnt(8)" ::: "memory");   // tile t done; t+1 in flight
    } else {
      asm volatile("s_waitcnt vmcnt(0)" ::: "memory");
    }
    __builtin_amdgcn_s_barrier();

    const ushort_t* A = &As[cur][0];
    const ushort_t* B = &Bs[cur][0];
    bf16x8 af[4][2], bfr[2][2];

    // ---- P0: read A(i=0..3) + B(j=0..1); MFMA quad (0..3)x(0..1)
#pragma unroll
    for (int ii = 0; ii < 4; ++ii) {
      af[ii][0] = *(const bf16x8*)&A[aoff[ii]];
      af[ii][1] = *(const bf16x8*)&A[aoff[ii] ^ 32];
    }
#pragma unroll
    for (int jj = 0; jj < 2; ++jj) {
      bfr[jj][0] = *(const bf16x8*)&B[boff[jj]];
      bfr[jj][1] = *(const bf16x8*)&B[boff[jj] ^ 32];
    }
    __builtin_amdgcn_s_barrier();
    asm volatile("s_waitcnt lgkmcnt(0)" ::: "memory");
    __builtin_amdgcn_s_setprio(1);
#pragma unroll
    for (int ii = 0; ii < 4; ++ii)
#pragma unroll
      for (int jj = 0; jj < 2; ++jj) {
        acc[ii][jj] = __builtin_amdgcn_mfma_f32_16x16x32_bf16(af[ii][0], bfr[jj][0], acc[ii][jj], 0, 0, 0);
        acc[ii][jj] = __builtin_amdgcn_mfma_f32_16x16x32_bf16(af[ii][1], bfr[jj][1], acc[ii][jj], 0, 0, 0);
      }
    __builtin_amdgcn_s_setprio(0);
    __builtin_amdgcn_s_barrier();

    // ---- P1: read B(j=2..3); MFMA quad (0..3)x(2..3)
#pragma unroll
    for (int jj = 0; jj < 2; ++jj) {
      bfr[jj][0] = *(const bf16x8*)&B[boff[2 + jj]];
      bfr[jj][1] = *(const bf16x8*)&B[boff[2 + jj] ^ 32];
    }
    __builtin_amdgcn_s_barrier();
    asm volatile("s_waitcnt lgkmcnt(0)" ::: "memory");
    __builtin_amdgcn_s_setprio(1);
#pragma unroll
    for (int ii = 0; ii < 4; ++ii)
#pragma unroll
      for (int jj = 0; jj < 2; ++jj) {
        acc[ii][2 + jj] = __builtin_amdgcn_mfma_f32_16x16x32_bf16(af[ii][0], bfr[jj][0], acc[ii][2 + jj], 0, 0, 0);
        acc[ii][2 + jj] = __builtin_amdgcn_mfma_f32_16x16x32_bf16(af[ii][1], bfr[jj][1], acc[ii][2 + jj], 0, 0, 0);
      }
    __builtin_amdgcn_s_setprio(0);
    __builtin_amdgcn_s_barrier();

    // ---- P2: read A(i=4..7); MFMA quad (4..7)x(2..3)  (bfr holds j=2..3)
#pragma unroll
    for (int ii = 0; ii < 4; ++ii) {
      af[ii][0] = *(const bf16x8*)&A[aoff[4 + ii]];
      af[ii][1] = *(const bf16x8*)&A[aoff[4 + ii] ^ 32];
    }
    __builtin_amdgcn_s_barrier();
    asm volatile("s_waitcnt lgkmcnt(0)" ::: "memory");
    __builtin_amdgcn_s_setprio(1);
#pragma unroll
    for (int ii = 0; ii < 4; ++ii)
#pragma unroll
      for (int jj = 0; jj < 2; ++jj) {
        acc[4 + ii][2 + jj] = __builtin_amdgcn_mfma_f32_16x16x32_bf16(af[ii][0], bfr[jj][0], acc[4 + ii][2 + jj], 0, 0, 0);
        acc[4 + ii][2 + jj] = __builtin_amdgcn_mfma_f32_16x16x32_bf16(af[ii][1], bfr[jj][1], acc[4 + ii][2 + jj], 0, 0, 0);
      }
    __builtin_amdgcn_s_setprio(0);
    __builtin_amdgcn_s_barrier();

    // ---- P3: read B(j=0..1); MFMA quad (4..7)x(0..1)  (af holds i=4..7)
#pragma unroll
    for (int jj = 0; jj < 2; ++jj) {
      bfr[jj][0] = *(const bf16x8*)&B[boff[jj]];
      bfr[jj][1] = *(const bf16x8*)&B[boff[jj] ^ 32];
    }
    __builtin_amdgcn_s_barrier();
    asm volatile("s_waitcnt lgkmcnt(0)" ::: "memory");
    __builtin_amdgcn_s_setprio(1);
#pragma unroll
    for (int ii = 0; ii < 4; ++ii)
#pragma unroll
      for (int jj = 0; jj < 2; ++jj) {
        acc[4 + ii][jj] = __builtin_amdgcn_mfma_f32_16x16x32_bf16(af[ii][0], bfr[jj][0], acc[4 + ii][jj], 0, 0, 0);
        acc[4 + ii][jj] = __builtin_amdgcn_mfma_f32_16x16x32_bf16(af[ii][1], bfr[jj][1], acc[4 + ii][jj], 0, 0, 0);
      }
    __builtin_amdgcn_s_setprio(0);
    __builtin_amdgcn_s_barrier();
  }

  // epilogue: frag pair (2jj, 2jj+1) = (gate, up); act col group g
#pragma unroll
  for (int i = 0; i < 8; ++i) {
    const int row = slot0 + wm * 128 + i * 16 + q * 4;
#pragma unroll
    for (int jj = 0; jj < 2; ++jj) {
      const int g = nb * 8 + wn * 2 + jj;
      const int col = g * 16 + r;
      const f32x4 gv = acc[i][2 * jj];
      const f32x4 uv = acc[i][2 * jj + 1];
#pragma unroll
      for (int reg = 0; reg < 4; ++reg) {
        float gate = gv[reg];
        float a = gate / (1.f + __expf(-gate)) * uv[reg];
        Act[(size_t)(row + reg) * I_DIM + col] = f2bf(a);
      }
    }
  }
}

// ---------------- GEMM2: Y[slot] = w_slot * (act @ W2^T), plain bf16 stores ----
__global__ __launch_bounds__(512, 2) void gemm2_kernel(
    const ushort_t* __restrict__ Act, const ushort_t* __restrict__ W2b,
    ushort_t* __restrict__ Y, const float* __restrict__ slot_w,
    const int* __restrict__ tile_expert, const int* __restrict__ ntl) {
  const int bid = blockIdx.x;
  const int wg = (bid & 7) * (NX2 * MAXMT / 8) + (bid >> 3);
  const int mt = wg >> 3;
  const int nb = wg & 7;
  if (mt >= ntl[0]) return;
  const int e = tile_expert[mt];
  const int slot0 = mt * BM;
  const int n0 = nb * BM;

  __shared__ ushort_t As[2][BM * BK];
  __shared__ ushort_t Bs[2][BM * BK];
  __shared__ float wgt[BM];

  const int tid = threadIdx.x;
  if (tid < BM) wgt[tid] = slot_w[slot0 + tid];
  __syncthreads();

  const int wave = tid >> 6;
  const int lane = tid & 63;
  const int r = lane & 15;
  const int q = lane >> 4;
  const int wm = wave >> 2;
  const int wn = wave & 3;

  const ushort_t* a_src[4];
  const ushort_t* b_src[4];
  int dst_u[4];
#pragma unroll
  for (int s = 0; s < 4; ++s) {
    int u = s * 512 + tid;
    int m = u >> 3;
    int kc = (u & 7) ^ (m & 7);
    a_src[s] = Act + (size_t)(slot0 + m) * I_DIM + kc * 8;
    b_src[s] = W2b + (size_t)e * ((size_t)H_DIM * I_DIM) + (size_t)(n0 + m) * I_DIM + kc * 8;
    dst_u[s] = u * 8;
  }

  int aoff[8], boff[4];
#pragma unroll
  for (int i = 0; i < 8; ++i) {
    int m = wm * 128 + i * 16 + r;
    aoff[i] = (m * 8 + (q ^ (m & 7))) * 8;
  }
#pragma unroll
  for (int j = 0; j < 4; ++j) {
    int n = wn * 64 + j * 16 + r;
    boff[j] = (n * 8 + (q ^ (n & 7))) * 8;
  }

  f32x4 acc[8][4];
#pragma unroll
  for (int i = 0; i < 8; ++i)
#pragma unroll
    for (int j = 0; j < 4; ++j) acc[i][j] = (f32x4)(0.f);

  const int NT = I_DIM / BK;   // 22

#pragma unroll
  for (int s = 0; s < 4; ++s) {
    async_copy16(a_src[s], &As[0][dst_u[s]]);
    async_copy16(b_src[s], &Bs[0][dst_u[s]]);
  }

  for (int t = 0; t < NT; ++t) {
    const int cur = t & 1;
    const int nxt = cur ^ 1;
    if (t + 1 < NT) {
      const int koff = (t + 1) * BK;
#pragma unroll
      for (int s = 0; s < 4; ++s) {
        async_copy16(a_src[s] + koff, &As[nxt][dst_u[s]]);
        async_copy16(b_src[s] + koff, &Bs[nxt][dst_u[s]]);
      }
      asm volatile("s_waitcnt vmcnt(8)" ::: "memory");
    } else {
      asm volatile("s_waitcnt vmcnt(0)" ::: "memory");
    }
    __builtin_amdgcn_s_barrier();

    const ushort_t* A = &As[cur][0];
    const ushort_t* B = &Bs[cur][0];
    bf16x8 af[4][2], bfr[2][2];

    // P0
#pragma unroll
    for (int ii = 0; ii < 4; ++ii) {
      af[ii][0] = *(const bf16x8*)&A[aoff[ii]];
      af[ii][1] = *(const bf16x8*)&A[aoff[ii] ^ 32];
    }
#pragma unroll
    for (int jj = 0; jj < 2; ++jj) {
      bfr[jj][0] = *(const bf16x8*)&B[boff[jj]];
      bfr[jj][1] = *(const bf16x8*)&B[boff[jj] ^ 32];
    }
    __builtin_amdgcn_s_barrier();
    asm volatile("s_waitcnt lgkmcnt(0)" ::: "memory");
    __builtin_amdgcn_s_setprio(1);
#pragma unroll
    for (int ii = 0; ii < 4; ++ii)
#pragma unroll
      for (int jj = 0; jj < 2; ++jj) {
        acc[ii][jj] = __builtin_amdgcn_mfma_f32_16x16x32_bf16(af[ii][0], bfr[jj][0], acc[ii][jj], 0, 0, 0);
        acc[ii][jj] = __builtin_amdgcn_mfma_f32_16x16x32_bf16(af[ii][1], bfr[jj][1], acc[ii][jj], 0, 0, 0);
      }
    __builtin_amdgcn_s_setprio(0);
    __builtin_amdgcn_s_barrier();

    // P1
#pragma unroll
    for (int jj = 0; jj < 2; ++jj) {
      bfr[jj][0] = *(const bf16x8*)&B[boff[2 + jj]];
      bfr[jj][1] = *(const bf16x8*)&B[boff[2 + jj] ^ 32];
    }
    __builtin_amdgcn_s_barrier();
    asm volatile("s_waitcnt lgkmcnt(0)" ::: "memory");
    __builtin_amdgcn_s_setprio(1);
#pragma unroll
    for (int ii = 0; ii < 4; ++ii)
#pragma unroll
      for (int jj = 0; jj < 2; ++jj) {
        acc[ii][2 + jj] = __builtin_amdgcn_mfma_f32_16x16x32_bf16(af[ii][0], bfr[jj][0], acc[ii][2 + jj], 0, 0, 0);
        acc[ii][2 + jj] = __builtin_amdgcn_mfma_f32_16x16x32_bf16(af[ii][1], bfr[jj][1], acc[ii][2 + jj], 0, 0, 0);
      }
    __builtin_amdgcn_s_setprio(0);
    __builtin_amdgcn_s_barrier();

    // P2
#pragma unroll
    for (int ii = 0; ii < 4; ++ii) {
      af[ii][0] = *(const bf16x8*)&A[aoff[4 + ii]];
      af[ii][1] = *(const bf16x8*)&A[aoff[4 + ii] ^ 32];
    }
    __builtin_amdgcn_s_barrier();
    asm volatile("s_waitcnt lgkmcnt(0)" ::: "memory");
    __builtin_amdgcn_s_setprio(1);
#pragma unroll
    for (int ii = 0; ii < 4; ++ii)
#pragma unroll
      for (int jj = 0; jj < 2; ++jj) {
        acc[4 + ii][2 + jj] = __builtin_amdgcn_mfma_f32_16x16x32_bf16(af[ii][0], bfr[jj][0], acc[4 + ii][2 + jj], 0, 0, 0);
        acc[4 + ii][2 + jj] = __builtin_amdgcn_mfma_f32_16x16x32_bf16(af[ii][1], bfr[jj][1], acc[4 + ii][2 + jj], 0, 0, 0);
      }
    __builtin_amdgcn_s_setprio(0);
    __builtin_amdgcn_s_barrier();

    // P3
#pragma unroll
    for (int jj = 0; jj < 2; ++jj) {
      bfr[jj][0] = *(const bf16x8*)&B[boff[jj]];
      bfr[jj][1] = *(const bf16x8*)&B[boff[jj] ^ 32];
    }
    __builtin_amdgcn_s_barrier();
    asm volatile("s_waitcnt lgkmcnt(0)" ::: "memory");
    __builtin_amdgcn_s_setprio(1);
#pragma unroll
    for (int ii = 0; ii < 4; ++ii)
#pragma unroll
      for (int jj = 0; jj < 2; ++jj) {
        acc[4 + ii][jj] = __builtin_amdgcn_mfma_f32_16x16x32_bf16(af[ii][0], bfr[jj][0], acc[4 + ii][jj], 0, 0, 0);
        acc[4 + ii][jj] = __builtin_amdgcn_mfma_f32_16x16x32_bf16(af[ii][1], bfr[jj][1], acc[4 + ii][jj], 0, 0, 0);
      }
    __builtin_amdgcn_s_setprio(0);
    __builtin_amdgcn_s_barrier();
  }

  // epilogue: weighted per-slot rows, plain bf16 stores
#pragma unroll
  for (int i = 0; i < 8; ++i) {
#pragma unroll
    for (int reg = 0; reg < 4; ++reg) {
      const int rl = wm * 128 + i * 16 + q * 4 + reg;
      const float w = wgt[rl];
      ushort_t* yrow = Y + (size_t)(slot0 + rl) * H_DIM + n0 + wn * 64;
#pragma unroll
      for (int j = 0; j < 4; ++j) yrow[j * 16 + r] = f2bf(w * acc[i][j][reg]);
    }
  }
}

// ---------------- combine: out[t] = Y[slot(t,0)] + Y[slot(t,1)] ----------------
__global__ __launch_bounds__(256) void combine_kernel(
    const ushort_t* __restrict__ Y, const int* __restrict__ tslot,
    float* __restrict__ Out) {
  const int t = blockIdx.x;
  const int c = threadIdx.x * 8;
  const int s1 = tslot[2 * t];
  const int s2 = tslot[2 * t + 1];
  const us8 y1 = *(const us8*)(Y + (size_t)s1 * H_DIM + c);
  const us8 y2 = *(const us8*)(Y + (size_t)s2 * H_DIM + c);
  float4 o0, o1;
  o0.x = bf2f(y1[0]) + bf2f(y2[0]);
  o0.y = bf2f(y1[1]) + bf2f(y2[1]);
  o0.z = bf2f(y1[2]) + bf2f(y2[2]);
  o0.w = bf2f(y1[3]) + bf2f(y2[3]);
  o1.x = bf2f(y1[4]) + bf2f(y2[4]);
  o1.y = bf2f(y1[5]) + bf2f(y2[5]);
  o1.z = bf2f(y1[6]) + bf2f(y2[6]);
  o1.w = bf2f(y1[7]) + bf2f(y2[7]);
  float4* dst = (float4*)(Out + (size_t)t * H_DIM + c);
  dst[0] = o0;
  dst[1] = o1;
}

// ---------------- launch ----------------
extern "C" void kernel_launch(void* const* d_in, const int* in_sizes, int n_in,
                              void* d_out, int out_size, void* d_ws, size_t ws_size,
                              hipStream_t stream) {
  const float* hidden = (const float*)d_in[0];
  const float* logits = (const float*)d_in[1];
  const float* w13    = (const float*)d_in[2];
  const float* w2     = (const float*)d_in[3];
  float* out = (float*)d_out;
  char* ws = (char*)d_ws;

  const size_t SZ_HID = (size_t)T_TOK * H_DIM * 2;           // 64 MiB
  const size_t SZ_W13 = (size_t)E_NUM * TWO_I * H_DIM * 2;   // 176 MiB
  const size_t SZ_W2  = (size_t)E_NUM * H_DIM * I_DIM * 2;   // 88 MiB
  const size_t SZ_Y   = (size_t)PMAX * H_DIM * 2;            // 144 MiB
  const size_t REGION0 = SZ_HID + SZ_W13;                    // 240 MiB

  size_t off = 0;
  ushort_t* hid_b = (ushort_t*)(ws + off); off += SZ_HID;
  ushort_t* w13p  = (ushort_t*)(ws + off); off += SZ_W13;
  // overlay region (dead after gemm1): w2b then Y
  ushort_t* w2b   = (ushort_t*)ws;                 // written only AFTER gemm1
  ushort_t* ybuf  = (ushort_t*)(ws + SZ_W2);       // written only by gemm2 (after gemm1)
  ushort_t* act   = (ushort_t*)(ws + off); off += (size_t)PMAX * I_DIM * 2;   // ~99 MiB
  int*   stok  = (int*)(ws + off);  off += (size_t)PMAX * 4;
  float* swt   = (float*)(ws + off); off += (size_t)PMAX * 4;
  int*   tok_e = (int*)(ws + off);  off += (size_t)T_TOK * 2 * 4;
  float* tok_w = (float*)(ws + off); off += (size_t)T_TOK * 2 * 4;
  int*   tslot = (int*)(ws + off);  off += (size_t)T_TOK * 2 * 4;
  int* counts = (int*)(ws + off); off += 256;
  int* fill   = (int*)(ws + off); off += 256;
  int* base_e = (int*)(ws + off); off += 256;
  int* texp   = (int*)(ws + off); off += MAXMT * 4;
  int* ntl    = (int*)(ws + off); off += 256;

  if (off > ws_size || SZ_W2 + SZ_Y > REGION0) {
    fprintf(stderr, "FusedMoE: ws too small: need %zu have %zu\n", off, ws_size);
    return;
  }

  zero_small<<<1, 64, 0, stream>>>(counts, fill, ntl);
  router_kernel<<<T_TOK / 256, 256, 0, stream>>>(logits, tok_e, tok_w, counts);
  scan_kernel<<<1, 64, 0, stream>>>(counts, base_e, texp, ntl);
  slot_init_kernel<<<(PMAX + 255) / 256, 256, 0, stream>>>(stok, swt);
  scatter_kernel<<<T_TOK / 256, 256, 0, stream>>>(tok_e, tok_w, base_e, fill, stok, swt, tslot);

  cvt_hidden<<<(T_TOK * H_DIM / 8) / 256, 256, 0, stream>>>(hidden, hid_b);
  cvt_w13<<<(unsigned)((size_t)E_NUM * TWO_I * H_DIM / 8 / 256), 256, 0, stream>>>(w13, w13p);

  gemm1_kernel<<<NX1 * MAXMT, 512, 0, stream>>>(hid_b, w13p, act, stok, texp, ntl);

  cvt_w2<<<(unsigned)((size_t)E_NUM * H_DIM * I_DIM / 8 / 256), 256, 0, stream>>>(w2, w2b);

  gemm2_kernel<<<NX2 * MAXMT, 512, 0, stream>>>(act, w2b, ybuf, swt, texp, ntl);

  combine_kernel<<<T_TOK, 256, 0, stream>>>(ybuf, tslot, out);
}

// Round 3
// 1653.273 us; speedup vs baseline: 1.1519x; 1.1519x over previous
//
#include <hip/hip_runtime.h>
#include <cstdio>
#include <cstdint>

// ---------------- problem constants ----------------
#define T_TOK 16384
#define H_DIM 2048
#define E_NUM 16
#define I_DIM 1408
#define TWO_I 2816
#define PMAX  34816     // 272*128: upper bound on padded slot count
#define MAXMT 272       // upper bound on m-tiles: 2*T/128 + E
#define NX1   22        // gemm1 n-blocks: 2816/128
#define NX2   16        // gemm2 n-blocks: 2048/128

typedef unsigned short ushort_t;
typedef __attribute__((ext_vector_type(8))) short bf16x8;
typedef __attribute__((ext_vector_type(4))) float f32x4;
typedef __attribute__((ext_vector_type(8))) unsigned short us8;

__device__ __forceinline__ ushort_t f2bf(float x) {
  union { float f; unsigned int u; } v; v.f = x;
  unsigned int r = v.u + 0x7fffu + ((v.u >> 16) & 1u);   // RNE
  return (ushort_t)(r >> 16);
}

__device__ __forceinline__ float bf2f(ushort_t u) {
  union { unsigned int i; float f; } v; v.i = ((unsigned int)u) << 16; return v.f;
}

__device__ __forceinline__ void async_copy16(const void* g, void* l) {
  __builtin_amdgcn_global_load_lds(
      (const __attribute__((address_space(1))) unsigned int*)g,
      (__attribute__((address_space(3))) unsigned int*)l, 16, 0, 0);
}

// ---------------- routing ----------------
__global__ void zero_small(int* counts, int* fill, int* ntl) {
  int i = threadIdx.x;
  if (i < E_NUM) { counts[i] = 0; fill[i] = 0; }
  if (i == 0) ntl[0] = 0;
}

__global__ void router_kernel(const float* __restrict__ logits,
                              int* __restrict__ tok_e, float* __restrict__ tok_w,
                              int* __restrict__ counts) {
  int t = blockIdx.x * 256 + threadIdx.x;
  if (t >= T_TOK) return;
  const float4* lp = (const float4*)(logits + (size_t)t * E_NUM);
  float4 v0 = lp[0], v1 = lp[1], v2 = lp[2], v3 = lp[3];
  float a[16] = {v0.x, v0.y, v0.z, v0.w, v1.x, v1.y, v1.z, v1.w,
                 v2.x, v2.y, v2.z, v2.w, v3.x, v3.y, v3.z, v3.w};
  float b1 = -1e30f, b2 = -1e30f; int i1 = 0, i2 = 0;
#pragma unroll
  for (int e = 0; e < E_NUM; ++e) {
    float v = a[e];
    if (v > b1) { b2 = b1; i2 = i1; b1 = v; i1 = e; }
    else if (v > b2) { b2 = v; i2 = e; }
  }
  // renormalized top-2 softmax: full denominator cancels
  float w1 = 1.f / (1.f + __expf(b2 - b1));
  tok_e[2 * t] = i1; tok_e[2 * t + 1] = i2;
  tok_w[2 * t] = w1; tok_w[2 * t + 1] = 1.f - w1;
  atomicAdd(&counts[i1], 1);
  atomicAdd(&counts[i2], 1);
}

// wave-parallel: lane e handles expert e; 128-padded tiles, contiguous bases
__global__ void scan_kernel(const int* __restrict__ counts, int* __restrict__ base_e,
                            int* __restrict__ tile_expert, int* __restrict__ ntl) {
  int lane = threadIdx.x;
  int c = (lane < E_NUM) ? counts[lane] : 0;
  int tiles = (c + 127) >> 7;
  int pre = 0;
#pragma unroll
  for (int k = 0; k < E_NUM; ++k) {
    int tk = __shfl(tiles, k, 64);
    if (k < lane) pre += tk;
  }
  if (lane < E_NUM) {
    base_e[lane] = pre << 7;
    for (int ti = 0; ti < tiles; ++ti) tile_expert[pre + ti] = lane;
    if (lane == E_NUM - 1) ntl[0] = pre + tiles;
  }
}

__global__ void slot_init_kernel(int* st, float* sw) {
  int i = blockIdx.x * 256 + threadIdx.x;
  if (i < PMAX) { st[i] = 0; sw[i] = 0.f; }   // pad slots: token 0, weight 0
}

__global__ void scatter_kernel(const int* __restrict__ tok_e, const float* __restrict__ tok_w,
                               const int* __restrict__ base_e, int* __restrict__ fill,
                               int* __restrict__ st, float* __restrict__ sw,
                               int* __restrict__ tslot) {
  int t = blockIdx.x * 256 + threadIdx.x;
  if (t >= T_TOK) return;
#pragma unroll
  for (int k = 0; k < 2; ++k) {
    int e = tok_e[2 * t + k];
    int pos = atomicAdd(&fill[e], 1);
    int slot = base_e[e] + pos;
    st[slot] = t; sw[slot] = tok_w[2 * t + k];
    tslot[2 * t + k] = slot;
  }
}

// ---------------- fp32 -> bf16 conversion ----------------
__device__ __forceinline__ us8 pack8(float4 a, float4 b) {
  us8 r;
  r[0] = f2bf(a.x); r[1] = f2bf(a.y); r[2] = f2bf(a.z); r[3] = f2bf(a.w);
  r[4] = f2bf(b.x); r[5] = f2bf(b.y); r[6] = f2bf(b.z); r[7] = f2bf(b.w);
  return r;
}

__global__ void cvt_hidden(const float* __restrict__ src, ushort_t* __restrict__ dst) {
  size_t i8 = ((size_t)blockIdx.x * 256 + threadIdx.x) * 8;
  const float4* s = (const float4*)(src + i8);
  *(us8*)(dst + i8) = pack8(s[0], s[1]);
}

// permute w13 rows, division-free: block = (row n, expert e); 256 threads cover H
// gate row n (<I) -> (n/16)*32 + n%16 ; up row n (>=I) -> ((n-I)/16)*32 + 16 + (n-I)%16
__global__ void cvt_w13(const float* __restrict__ src, ushort_t* __restrict__ dst) {
  const int n = blockIdx.x;
  const int e = blockIdx.y;
  const int c = threadIdx.x * 8;
  int np;
  if (n < I_DIM) np = ((n >> 4) << 5) + (n & 15);
  else { int m = n - I_DIM; np = ((m >> 4) << 5) + 16 + (m & 15); }
  const size_t per_e = (size_t)TWO_I * H_DIM;
  const float4* s = (const float4*)(src + (size_t)e * per_e + (size_t)n * H_DIM + c);
  *(us8*)(dst + (size_t)e * per_e + (size_t)np * H_DIM + c) = pack8(s[0], s[1]);
}

__global__ void cvt_w2(const float* __restrict__ src, ushort_t* __restrict__ dst) {
  size_t i8 = ((size_t)blockIdx.x * 256 + threadIdx.x) * 8;
  const float4* s = (const float4*)(src + i8);
  *(us8*)(dst + i8) = pack8(s[0], s[1]);
}

// ---------------- GEMM1: act = silu(X @ W1^T) * (X @ W3^T), token-gathered A ----------------
// LDS swizzle: 16B cell for (row m, k-chunk kc) lives at unit m*8 + (kc ^ (m&7)).
// Conflict-free ds_read_b128 frag reads AND lane-contiguous global_load_lds staging.
// Grid: 1D, m-tile-fastest order + bijective XCD chunk swizzle (B-slice L2 reuse).
__global__ __launch_bounds__(256, 2) void gemm1_kernel(
    const ushort_t* __restrict__ Xb, const ushort_t* __restrict__ W13p,
    ushort_t* __restrict__ Act, const int* __restrict__ slot_token,
    const int* __restrict__ tile_expert, const int* __restrict__ ntl) {
  const int CH = NX1 * MAXMT / 8;                 // 748
  const int bid = blockIdx.x;
  const int wg = (bid & 7) * CH + (bid >> 3);     // bijective XCD chunking
  const int mt = wg % MAXMT;                      // m-tile fastest within chunk
  const int nb = wg / MAXMT;
  if (mt >= ntl[0]) return;
  const int e = tile_expert[mt];
  const int slot0 = mt * 128;
  const int n0 = nb * 128;

  __shared__ ushort_t As[128 * 64];
  __shared__ ushort_t Bs[128 * 64];
  __shared__ int toks[128];

  const int tid = threadIdx.x;
  if (tid < 128) toks[tid] = slot_token[slot0 + tid];
  __syncthreads();

  const int wave = tid >> 6;
  const int lane = tid & 63;
  const int r = lane & 15;
  const int q = lane >> 4;
  const int wm = wave >> 1;
  const int wn = wave & 1;

  const ushort_t* a_src[4];
  const ushort_t* b_src[4];
  ushort_t* a_dst[4];
  ushort_t* b_dst[4];
#pragma unroll
  for (int s = 0; s < 4; ++s) {
    int u = wave * 256 + s * 64 + lane;
    int m = u >> 3;
    int kc = (u & 7) ^ (m & 7);
    a_src[s] = Xb + (size_t)toks[m] * H_DIM + kc * 8;
    b_src[s] = W13p + (size_t)e * ((size_t)TWO_I * H_DIM) + (size_t)(n0 + m) * H_DIM + kc * 8;
    a_dst[s] = &As[(size_t)u * 8];
    b_dst[s] = &Bs[(size_t)u * 8];
  }

  int aoff[2][4], boff[2][4];
#pragma unroll
  for (int kh = 0; kh < 2; ++kh)
#pragma unroll
    for (int i = 0; i < 4; ++i) {
      int m = wm * 64 + i * 16 + r;
      aoff[kh][i] = (m * 8 + ((kh * 4 + q) ^ (r & 7))) * 8;
      int n = wn * 64 + i * 16 + r;
      boff[kh][i] = (n * 8 + ((kh * 4 + q) ^ (r & 7))) * 8;
    }

  f32x4 acc[4][4];
#pragma unroll
  for (int i = 0; i < 4; ++i)
#pragma unroll
    for (int j = 0; j < 4; ++j) acc[i][j] = (f32x4)(0.f);

  for (int kt = 0; kt < H_DIM / 64; ++kt) {
    const int koff = kt * 64;
#pragma unroll
    for (int s = 0; s < 4; ++s) {
      async_copy16(a_src[s] + koff, a_dst[s]);
      async_copy16(b_src[s] + koff, b_dst[s]);
    }
    __syncthreads();
#pragma unroll
    for (int kh = 0; kh < 2; ++kh) {
      bf16x8 af[4], bfr[4];
#pragma unroll
      for (int i = 0; i < 4; ++i) af[i] = *(const bf16x8*)&As[aoff[kh][i]];
#pragma unroll
      for (int j = 0; j < 4; ++j) bfr[j] = *(const bf16x8*)&Bs[boff[kh][j]];
#pragma unroll
      for (int i = 0; i < 4; ++i)
#pragma unroll
        for (int j = 0; j < 4; ++j)
          acc[i][j] = __builtin_amdgcn_mfma_f32_16x16x32_bf16(af[i], bfr[j], acc[i][j], 0, 0, 0);
    }
    __syncthreads();
  }

  // epilogue: frag pair (2jj, 2jj+1) = (gate, up) for act column group g
#pragma unroll
  for (int i = 0; i < 4; ++i) {
    const int row = slot0 + wm * 64 + i * 16 + q * 4;
#pragma unroll
    for (int jj = 0; jj < 2; ++jj) {
      const int g = 4 * nb + 2 * wn + jj;
      const int col = g * 16 + r;
      const f32x4 gv = acc[i][2 * jj];
      const f32x4 uv = acc[i][2 * jj + 1];
#pragma unroll
      for (int reg = 0; reg < 4; ++reg) {
        float gate = gv[reg];
        float a = gate / (1.f + __expf(-gate)) * uv[reg];
        Act[(size_t)(row + reg) * I_DIM + col] = f2bf(a);
      }
    }
  }
}

// ---------------- GEMM2: Y[slot] = w_slot * (act @ W2^T)  (plain bf16 stores) ----------------
__global__ __launch_bounds__(256, 2) void gemm2_kernel(
    const ushort_t* __restrict__ Act, const ushort_t* __restrict__ W2b,
    ushort_t* __restrict__ Y, const float* __restrict__ slot_w,
    const int* __restrict__ tile_expert, const int* __restrict__ ntl) {
  const int CH = NX2 * MAXMT / 8;                 // 544
  const int bid = blockIdx.x;
  const int wg = (bid & 7) * CH + (bid >> 3);
  const int mt = wg % MAXMT;
  const int nb = wg / MAXMT;
  if (mt >= ntl[0]) return;
  const int e = tile_expert[mt];
  const int slot0 = mt * 128;
  const int n0 = nb * 128;

  __shared__ ushort_t As[128 * 64];
  __shared__ ushort_t Bs[128 * 64];
  __shared__ float wgt[128];

  const int tid = threadIdx.x;
  if (tid < 128) wgt[tid] = slot_w[slot0 + tid];

  const int wave = tid >> 6;
  const int lane = tid & 63;
  const int r = lane & 15;
  const int q = lane >> 4;
  const int wm = wave >> 1;
  const int wn = wave & 1;

  const ushort_t* a_src[4];
  const ushort_t* b_src[4];
  ushort_t* a_dst[4];
  ushort_t* b_dst[4];
#pragma unroll
  for (int s = 0; s < 4; ++s) {
    int u = wave * 256 + s * 64 + lane;
    int m = u >> 3;
    int kc = (u & 7) ^ (m & 7);
    a_src[s] = Act + (size_t)(slot0 + m) * I_DIM + kc * 8;
    b_src[s] = W2b + (size_t)e * ((size_t)H_DIM * I_DIM) + (size_t)(n0 + m) * I_DIM + kc * 8;
    a_dst[s] = &As[(size_t)u * 8];
    b_dst[s] = &Bs[(size_t)u * 8];
  }

  int aoff[2][4], boff[2][4];
#pragma unroll
  for (int kh = 0; kh < 2; ++kh)
#pragma unroll
    for (int i = 0; i < 4; ++i) {
      int m = wm * 64 + i * 16 + r;
      aoff[kh][i] = (m * 8 + ((kh * 4 + q) ^ (r & 7))) * 8;
      int n = wn * 64 + i * 16 + r;
      boff[kh][i] = (n * 8 + ((kh * 4 + q) ^ (r & 7))) * 8;
    }

  f32x4 acc[4][4];
#pragma unroll
  for (int i = 0; i < 4; ++i)
#pragma unroll
    for (int j = 0; j < 4; ++j) acc[i][j] = (f32x4)(0.f);

  for (int kt = 0; kt < I_DIM / 64; ++kt) {
    const int koff = kt * 64;
#pragma unroll
    for (int s = 0; s < 4; ++s) {
      async_copy16(a_src[s] + koff, a_dst[s]);
      async_copy16(b_src[s] + koff, b_dst[s]);
    }
    __syncthreads();
#pragma unroll
    for (int kh = 0; kh < 2; ++kh) {
      bf16x8 af[4], bfr[4];
#pragma unroll
      for (int i = 0; i < 4; ++i) af[i] = *(const bf16x8*)&As[aoff[kh][i]];
#pragma unroll
      for (int j = 0; j < 4; ++j) bfr[j] = *(const bf16x8*)&Bs[boff[kh][j]];
#pragma unroll
      for (int i = 0; i < 4; ++i)
#pragma unroll
        for (int j = 0; j < 4; ++j)
          acc[i][j] = __builtin_amdgcn_mfma_f32_16x16x32_bf16(af[i], bfr[j], acc[i][j], 0, 0, 0);
    }
    __syncthreads();
  }

  // epilogue: weighted per-slot rows, plain bf16 stores (combine sums the 2 slots/token)
#pragma unroll
  for (int i = 0; i < 4; ++i) {
#pragma unroll
    for (int reg = 0; reg < 4; ++reg) {
      const int rl = wm * 64 + i * 16 + q * 4 + reg;
      const float w = wgt[rl];
      ushort_t* yrow = Y + (size_t)(slot0 + rl) * H_DIM;
#pragma unroll
      for (int j = 0; j < 4; ++j) {
        const int col = n0 + wn * 64 + j * 16 + r;
        yrow[col] = f2bf(w * acc[i][j][reg]);
      }
    }
  }
}

// ---------------- combine: out[t] = Y[slot(t,0)] + Y[slot(t,1)] ----------------
__global__ __launch_bounds__(256) void combine_kernel(
    const ushort_t* __restrict__ Y, const int* __restrict__ tslot,
    float* __restrict__ Out) {
  const int t = blockIdx.x;
  const int c = threadIdx.x * 8;
  const int s1 = tslot[2 * t];
  const int s2 = tslot[2 * t + 1];
  const us8 y1 = *(const us8*)(Y + (size_t)s1 * H_DIM + c);
  const us8 y2 = *(const us8*)(Y + (size_t)s2 * H_DIM + c);
  float4 o0, o1;
  o0.x = bf2f(y1[0]) + bf2f(y2[0]);
  o0.y = bf2f(y1[1]) + bf2f(y2[1]);
  o0.z = bf2f(y1[2]) + bf2f(y2[2]);
  o0.w = bf2f(y1[3]) + bf2f(y2[3]);
  o1.x = bf2f(y1[4]) + bf2f(y2[4]);
  o1.y = bf2f(y1[5]) + bf2f(y2[5]);
  o1.z = bf2f(y1[6]) + bf2f(y2[6]);
  o1.w = bf2f(y1[7]) + bf2f(y2[7]);
  float4* dst = (float4*)(Out + (size_t)t * H_DIM + c);
  dst[0] = o0;
  dst[1] = o1;
}

// ---------------- launch ----------------
extern "C" void kernel_launch(void* const* d_in, const int* in_sizes, int n_in,
                              void* d_out, int out_size, void* d_ws, size_t ws_size,
                              hipStream_t stream) {
  const float* hidden = (const float*)d_in[0];
  const float* logits = (const float*)d_in[1];
  const float* w13    = (const float*)d_in[2];
  const float* w2     = (const float*)d_in[3];
  float* out = (float*)d_out;
  char* ws = (char*)d_ws;

  const size_t SZ_HID = (size_t)T_TOK * H_DIM * 2;           // 64 MiB
  const size_t SZ_W13 = (size_t)E_NUM * TWO_I * H_DIM * 2;   // 176 MiB
  const size_t SZ_W2  = (size_t)E_NUM * H_DIM * I_DIM * 2;   // 88 MiB
  const size_t SZ_Y   = (size_t)PMAX * H_DIM * 2;            // 136 MiB
  const size_t REGION0 = SZ_HID + SZ_W13;                    // 240 MiB

  size_t off = 0;
  ushort_t* hid_b = (ushort_t*)(ws + off); off += SZ_HID;
  ushort_t* w13p  = (ushort_t*)(ws + off); off += SZ_W13;
  // overlay region (dead after gemm1): w2b then Y
  ushort_t* w2b   = (ushort_t*)ws;                 // written only AFTER gemm1
  ushort_t* ybuf  = (ushort_t*)(ws + SZ_W2);       // written only by gemm2 (after gemm1)
  ushort_t* act   = (ushort_t*)(ws + off); off += (size_t)PMAX * I_DIM * 2;   // 93.5 MiB
  int*   stok  = (int*)(ws + off);  off += (size_t)PMAX * 4;
  float* swt   = (float*)(ws + off); off += (size_t)PMAX * 4;
  int*   tok_e = (int*)(ws + off);  off += (size_t)T_TOK * 2 * 4;
  float* tok_w = (float*)(ws + off); off += (size_t)T_TOK * 2 * 4;
  int*   tslot = (int*)(ws + off);  off += (size_t)T_TOK * 2 * 4;
  int* counts = (int*)(ws + off); off += 256;
  int* fill   = (int*)(ws + off); off += 256;
  int* base_e = (int*)(ws + off); off += 256;
  int* texp   = (int*)(ws + off); off += MAXMT * 4;
  int* ntl    = (int*)(ws + off); off += 256;

  if (off > ws_size || SZ_W2 + SZ_Y > REGION0) {
    fprintf(stderr, "FusedMoE: ws too small: need %zu have %zu\n", off, ws_size);
    return;
  }

  zero_small<<<1, 64, 0, stream>>>(counts, fill, ntl);
  router_kernel<<<T_TOK / 256, 256, 0, stream>>>(logits, tok_e, tok_w, counts);
  scan_kernel<<<1, 64, 0, stream>>>(counts, base_e, texp, ntl);
  slot_init_kernel<<<(PMAX + 255) / 256, 256, 0, stream>>>(stok, swt);
  scatter_kernel<<<T_TOK / 256, 256, 0, stream>>>(tok_e, tok_w, base_e, fill, stok, swt, tslot);

  cvt_hidden<<<(T_TOK * H_DIM / 8) / 256, 256, 0, stream>>>(hidden, hid_b);
  {
    dim3 gw13(TWO_I, E_NUM);
    cvt_w13<<<gw13, 256, 0, stream>>>(w13, w13p);
  }

  gemm1_kernel<<<NX1 * MAXMT, 256, 0, stream>>>(hid_b, w13p, act, stok, texp, ntl);

  cvt_w2<<<(unsigned)((size_t)E_NUM * H_DIM * I_DIM / 8 / 256), 256, 0, stream>>>(w2, w2b);

  gemm2_kernel<<<NX2 * MAXMT, 256, 0, stream>>>(act, w2b, ybuf, swt, texp, ntl);

  combine_kernel<<<T_TOK, 256, 0, stream>>>(ybuf, tslot, out);
}